// Round 7
// baseline (83.905 us; speedup 1.0000x reference)
//
#include <hip/hip_runtime.h>

// Problem constants (reference: shape (2,1,160,192,160), win=9)
#define BB 2
#define DD 160
#define HH 192
#define WW 160
#define HW (HH * WW)
#define PAD 4
#define TH 16
#define TW 16
#define EXT 24              // TH+2*PAD == TW+2*PAD
#define XSTR 28             // plane row stride (words; rows 16B-aligned)
#define PLANE 768           // words per (parity,arr) plane (>= EXT*XSTR=672)
#define WCS 456             // wsum channel stride
#define WJS 28              // wsum j(col) stride (r contiguous, 16B-aligned)
#define WPS (5 * WCS)       // wsum parity stride (2280)
#define HCS 272             // hsum channel stride
#define HHS 17              // hsum row stride
#define HPS (5 * HCS)       // hsum parity stride (1360)
#define CHUNK 25
#define NCH 7               // ceil(DD/CHUNK)
#define NITER 33            // CHUNK + 2*PAD (staged slices per chunk)
#define TOT 36              // NITER + 3 pipeline stages, = 4*9
#define WT (WW / TW)        // 10
#define HT (HH / TH)        // 12
#define NBLK (WT * HT * NCH * BB)  // 1680
#define NTASK 288           // staging float4 tasks per slice
#define EPS 1e-5f
#define INV_WS (1.0f / 729.0f)

#define LD24(DST, SRC) do {                        \
    float4 _a0 = *(const float4*)((SRC));          \
    float4 _a1 = *(const float4*)((SRC) + 4);      \
    float4 _a2 = *(const float4*)((SRC) + 8);      \
    float4 _a3 = *(const float4*)((SRC) + 12);     \
    float4 _a4 = *(const float4*)((SRC) + 16);     \
    float4 _a5 = *(const float4*)((SRC) + 20);     \
    DST[0]=_a0.x; DST[1]=_a0.y; DST[2]=_a0.z; DST[3]=_a0.w;     \
    DST[4]=_a1.x; DST[5]=_a1.y; DST[6]=_a1.z; DST[7]=_a1.w;     \
    DST[8]=_a2.x; DST[9]=_a2.y; DST[10]=_a2.z; DST[11]=_a2.w;   \
    DST[12]=_a3.x; DST[13]=_a3.y; DST[14]=_a3.z; DST[15]=_a3.w; \
    DST[16]=_a4.x; DST[17]=_a4.y; DST[18]=_a4.z; DST[19]=_a4.w; \
    DST[20]=_a5.x; DST[21]=_a5.y; DST[22]=_a5.z; DST[23]=_a5.w; \
  } while (0)

// barrier that waits LDS only — never drains vmcnt (keeps prefetch in flight)
__device__ __forceinline__ void bar_lgkm() {
  asm volatile("s_waitcnt lgkmcnt(0)" ::: "memory");
  __builtin_amdgcn_s_barrier();
  asm volatile("" ::: "memory");
}

__global__ void __launch_bounds__(256) k_lncc(
    const float* __restrict__ x, const float* __restrict__ y,
    float* __restrict__ partials)
{
  __shared__ __align__(16) float sbuf[2][2][PLANE];  // [parity][arr] 12288 B
  __shared__ __align__(16) float wsum[2 * WPS];      // 18240 B [p][c][j][r]
  __shared__ __align__(16) float hsum[2 * HPS];      // 10880 B [p][c][h*HHS+w]
  __shared__ float red[4];

  const int t = threadIdx.x;
  const int w0 = blockIdx.x * TW;
  const int h0 = blockIdx.y * TH;
  const int bz = blockIdx.z;
  const int b = bz / NCH;
  const int chunk = bz - b * NCH;
  const int dc0 = chunk * CHUNK;
  const int g0 = dc0 - PAD;

  // ---- init: zero both parity planes (OOB slots stay 0 forever) ----
  for (int i = t; i < 2 * 2 * PLANE; i += 256) (&sbuf[0][0][0])[i] = 0.f;

  // ---- staging descriptors: NTASK float4 tasks; thread t gets t, 256+t ----
  int la0, la1; bool tk0, tk1;
  const float* gp0; const float* gp1;
  {
    const float* bx = x + (long)b * DD * HW;
    const float* by = y + (long)b * DD * HW;
#define MKTASK(TAU, LA, TK, GP)                                           \
    {                                                                     \
      int tau = (TAU);                                                    \
      int a = tau / 144;                                                  \
      int rem = tau - 144 * a;                                            \
      int r = rem / 6;                                                    \
      int q = rem - 6 * r;                                                \
      int aa = (a < 2) ? a : 0;                                           \
      int gh = h0 - PAD + r;                                              \
      int gw = w0 - PAD + 4 * q;                                          \
      bool ok = (tau < NTASK) && ((unsigned)gh < (unsigned)HH) &&         \
                ((unsigned)gw < (unsigned)WW);                            \
      LA = aa * PLANE + r * XSTR + 4 * q;                                 \
      TK = ok;                                                            \
      GP = (aa ? by : bx) + (ok ? (gh * WW + gw) : 0);                    \
    }
    MKTASK(t, la0, tk0, gp0)
    MKTASK(256 + t, la1, tk1, gp1)
#undef MKTASK
  }

  // ---- P2 constants (t<120): task = (channel c2, ext row r2) ----
  // c0: x, c1: y, c2: x*x, c3: y*y, c4: x*y (only c4 reads a B row)
  const int c2 = t / 24, r2 = t - c2 * 24;
  const int arrA = ((c2 == 1) || (c2 == 3)) ? 1 : 0;
  const bool needB = (c2 == 4);
  const bool sqA = (c2 == 2) || (c2 == 3);
  const int paOff = arrA * PLANE + r2 * XSTR;
  const int pbOff = PLANE + r2 * XSTR;          // y row (B of c4)
  const int wwOff = c2 * WCS + r2;              // + parity*WPS + j*WJS

  // ---- P3 constants (t<80): task = (channel c3, out col w3) ----
  const int c3 = t / 16, w3 = t - c3 * 16;
  const int wrOff = c3 * WCS + w3 * WJS;        // + parity*WPS, i contiguous
  const int hwOff = c3 * HCS + w3;              // + parity*HPS + h*HHS

  // ---- P4 constants ----
  const int h4 = t >> 4, w4 = t & 15;
  const int hrOff = h4 * HHS + w4;              // + parity*HPS + c*HCS

  // ---- D-window ring (static idx via jj), running sums ----
  float ring[9][5];
#pragma unroll
  for (int i = 0; i < 9; ++i)
#pragma unroll
    for (int c = 0; c < 5; ++c) ring[i][c] = 0.f;
  float run0 = 0.f, run1 = 0.f, run2 = 0.f, run3 = 0.f, run4 = 0.f, acc = 0.f;

  __syncthreads();   // zero-init visible

  // ---- prologue: prefetch slice k=0 (g0) ----
  float4 st0 = make_float4(0, 0, 0, 0), st1 = st0;
  bool ps0 = false, ps1 = false;
  if (g0 >= 0) {
    const long so = (long)g0 * HW;
    ps0 = tk0; if (ps0) st0 = *(const float4*)(gp0 + so);
    ps1 = tk1; if (ps1) st1 = *(const float4*)(gp1 + so);
  }

  // ---- pipelined main loop: iter k runs STORE(k) | P2(k-1) | P3(k-2) | P4(k-3)
  for (int ko = 0; ko < 4; ++ko) {
#pragma unroll
    for (int jj = 0; jj < 9; ++jj) {
      const int k = ko * 9 + jj;
      const int gst = g0 + k;

      bar_lgkm();  // all LDS writes of iter k-1 visible; vmem stays in flight

      // ---- STORE slice k -> sbuf[k&1] ----
      if ((k < NITER) && ((unsigned)gst < (unsigned)DD)) {
        float* lb = &sbuf[k & 1][0][0];
        if (ps0) *(float4*)(lb + la0) = st0;
        if (ps1) *(float4*)(lb + la1) = st1;
      }
      // ---- prefetch slice k+1 (in flight across everything below) ----
      {
        const int gn = gst + 1;
        const bool nv = (k + 1 < NITER) && ((unsigned)gn < (unsigned)DD);
        const long so = (long)gn * HW;
        ps0 = tk0 && nv; if (ps0) st0 = *(const float4*)(gp0 + so);
        ps1 = tk1 && nv; if (ps1) st1 = *(const float4*)(gp1 + so);
      }

      // ---- P2: W-filter of slice k-1 (reads sbuf[(k-1)&1], writes wsum[(k-1)&1]) ----
      if ((k >= 1) && (k <= NITER) && ((unsigned)(gst - 1) < (unsigned)DD)) {
        if (t < 120) {
          const int pp = (k - 1) & 1;
          const float* base2 = &sbuf[pp][0][0];
          float av[EXT];
          LD24(av, base2 + paOff);
          float bv[EXT];
          if (needB) {
            LD24(bv, base2 + pbOff);
          } else {
#pragma unroll
            for (int i = 0; i < EXT; ++i) bv[i] = sqA ? av[i] : 1.0f;
          }
          float qv[EXT];
#pragma unroll
          for (int i = 0; i < EXT; ++i) qv[i] = av[i] * bv[i];
          float s = ((qv[0] + qv[1]) + (qv[2] + qv[3])) +
                    ((qv[4] + qv[5]) + (qv[6] + qv[7])) + qv[8];
          float* wq = &wsum[pp * WPS + wwOff];
          wq[0] = s;
#pragma unroll
          for (int j = 1; j < TW; ++j) {
            s += qv[j + 8] - qv[j - 1];
            wq[j * WJS] = s;
          }
        }
      }

      // ---- P3: H-filter of slice k-2 (reads wsum[k&1], writes hsum[k&1]) ----
      if ((k >= 2) && (k <= NITER + 1) && ((unsigned)(gst - 2) < (unsigned)DD)) {
        if (t < 80) {
          const int pp = k & 1;
          const float* wr3 = &wsum[pp * WPS + wrOff];
          float vv[EXT];
          LD24(vv, wr3);
          float s = ((vv[0] + vv[1]) + (vv[2] + vv[3])) +
                    ((vv[4] + vv[5]) + (vv[6] + vv[7])) + vv[8];
          float* hq = &hsum[pp * HPS + hwOff];
          hq[0] = s;
#pragma unroll
          for (int h = 1; h < TH; ++h) {
            s += vv[h + 8] - vv[h - 1];
            hq[h * HHS] = s;
          }
        }
      }

      // ---- P4: consume slice k-3 (reads hsum[(k+1)&1]) + ring + cc ----
      float hv0 = 0.f, hv1 = 0.f, hv2 = 0.f, hv3 = 0.f, hv4 = 0.f;
      if ((k >= 3) && ((unsigned)(gst - 3) < (unsigned)DD)) {
        const float* hb = &hsum[((k + 1) & 1) * HPS + hrOff];
        hv0 = hb[0];
        hv1 = hb[HCS];
        hv2 = hb[2 * HCS];
        hv3 = hb[3 * HCS];
        hv4 = hb[4 * HCS];
      }
      run0 += hv0 - ring[jj][0]; ring[jj][0] = hv0;
      run1 += hv1 - ring[jj][1]; ring[jj][1] = hv1;
      run2 += hv2 - ring[jj][2]; ring[jj][2] = hv2;
      run3 += hv3 - ring[jj][3]; ring[jj][3] = hv3;
      run4 += hv4 - ring[jj][4]; ring[jj][4] = hv4;

      if (k >= 11) {
        const int d = dc0 + (k - 11);
        if (d < DD) {                 // block-uniform tail guard
          float cross = fmaf(-run0 * INV_WS, run1, run4);
          float xv = fmaxf(fmaf(-run0 * INV_WS, run0, run2), EPS);
          float yv = fmaxf(fmaf(-run1 * INV_WS, run1, run3), EPS);
          acc += (cross * cross) * __builtin_amdgcn_rcpf(xv * yv);
        }
      }
    }
  }

  // ---- block reduction ----
#pragma unroll
  for (int o = 32; o > 0; o >>= 1) acc += __shfl_down(acc, o);
  __syncthreads();
  if ((t & 63) == 0) red[t >> 6] = acc;
  __syncthreads();
  if (t == 0) {
    int bid = (bz * HT + blockIdx.y) * WT + blockIdx.x;
    partials[bid] = (red[0] + red[1]) + (red[2] + red[3]);
  }
}

__global__ void __launch_bounds__(256) k_finalize(
    const float* __restrict__ partials, float* __restrict__ out)
{
  __shared__ double red[256];
  double s = 0.0;
  for (int i = threadIdx.x; i < NBLK; i += 256) s += (double)partials[i];
  red[threadIdx.x] = s;
  __syncthreads();
  for (int o = 128; o > 0; o >>= 1) {
    if (threadIdx.x < o) red[threadIdx.x] += red[threadIdx.x + o];
    __syncthreads();
  }
  if (threadIdx.x == 0) {
    const double Nvox = (double)BB * DD * HH * WW;
    out[0] = (float)(-red[0] / Nvox);
  }
}

extern "C" void kernel_launch(void* const* d_in, const int* in_sizes, int n_in,
                              void* d_out, int out_size, void* d_ws, size_t ws_size,
                              hipStream_t stream) {
  (void)in_sizes; (void)n_in; (void)out_size; (void)ws_size;
  const float* x = (const float*)d_in[0];
  const float* y = (const float*)d_in[1];
  float* out = (float*)d_out;
  float* partials = (float*)d_ws;

  dim3 grid(WT, HT, BB * NCH);
  k_lncc<<<grid, 256, 0, stream>>>(x, y, partials);
  k_finalize<<<1, 256, 0, stream>>>(partials, out);
}

// Round 8
// 81.619 us; speedup vs baseline: 1.0280x; 1.0280x over previous
//
#include <hip/hip_runtime.h>

// Problem constants (reference: shape (2,1,160,192,160), win=9)
#define BB 2
#define DD 160
#define HH 192
#define WW 160
#define HW (HH * WW)
#define PAD 4
#define TH 16
#define TW 32
#define EXTH 24             // TH + 2*PAD
#define EXTW 40             // TW + 2*PAD
#define XSTR 40             // sbuf row stride (words); rows 160B, 16B-aligned
#define APL 960             // per-array plane words (EXTH*XSTR)
#define WRS 36              // wsum row stride (32 outs + 4 pad)
#define WCSTR 864           // wsum channel stride (EXTH*WRS); 864%32==0
#define HRS 36              // hsum row stride
#define HCSTR 576           // hsum channel stride (TH*HRS)
#define CHUNK 19
#define NCH 9               // ceil(160/19): last chunk has 8 outputs
#define NITER 27            // CHUNK + 2*PAD = 3*9 (static ring indexing)
#define WT (WW / TW)        // 5
#define HT (HH / TH)        // 12
#define NBLK (WT * HT * NCH * BB)   // 1080
#define NTASK 480           // staging float4 tasks: 2 arrays x 24 rows x 10 groups
#define EPS 1e-5f
#define INV_WS (1.0f / 729.0f)

// barrier that waits LDS only — never drains vmcnt (keeps prefetch in flight)
__device__ __forceinline__ void bar_lgkm() {
  asm volatile("s_waitcnt lgkmcnt(0)" ::: "memory");
  __builtin_amdgcn_s_barrier();
  asm volatile("" ::: "memory");
}

__device__ __forceinline__ float4 f4add(float4 a, float4 b) {
  return make_float4(a.x + b.x, a.y + b.y, a.z + b.z, a.w + b.w);
}
// s + p - m, componentwise
__device__ __forceinline__ float4 f4pm(float4 s, float4 p, float4 m) {
  return make_float4(s.x + p.x - m.x, s.y + p.y - m.y,
                     s.z + p.z - m.z, s.w + p.w - m.w);
}

__global__ void __launch_bounds__(256) k_lncc(
    const float* __restrict__ x, const float* __restrict__ y,
    float* __restrict__ partials)
{
  __shared__ __align__(16) float sb[2 * APL];     // x,y ext planes  7680 B
  __shared__ __align__(16) float ws[5 * WCSTR];   // W-filtered      17280 B
  __shared__ __align__(16) float hs[5 * HCSTR];   // W+H-filtered    11520 B
  __shared__ float red[4];

  const int t = threadIdx.x;
  const int w0 = blockIdx.x * TW;
  const int h0 = blockIdx.y * TH;
  const int bz = blockIdx.z;
  const int b = bz / NCH;
  const int chunk = bz - b * NCH;
  const int dc0 = chunk * CHUNK;
  const int g0 = dc0 - PAD;

  // ---- zero planes once (OOB slots stay 0 forever) ----
  for (int i = t; i < 2 * APL; i += 256) sb[i] = 0.f;

  // ---- staging descriptors: 480 float4 tasks; thread t gets t and t+256 ----
  int la0, la1; bool tk0, tk1;
  const float* gp0; const float* gp1;
  {
    const float* bx = x + (long)b * DD * HW;
    const float* by = y + (long)b * DD * HW;
#define MKTASK(TAU, LA, TK, GP)                                           \
    {                                                                     \
      int tau = (TAU);                                                    \
      int a = tau / 240;                                                  \
      int rem = tau - 240 * a;                                            \
      int r = rem / 10;                                                   \
      int q = rem - 10 * r;                                               \
      int aa = (a < 2) ? a : 0;                                           \
      int gh = h0 - PAD + r;                                              \
      int gw = w0 - PAD + 4 * q;                                          \
      bool ok = (tau < NTASK) && ((unsigned)gh < (unsigned)HH) &&         \
                ((unsigned)gw < (unsigned)WW);                            \
      LA = aa * APL + r * XSTR + 4 * q;                                   \
      TK = ok;                                                            \
      GP = (aa ? by : bx) + (ok ? (gh * WW + gw) : 0);                    \
    }
    MKTASK(t, la0, tk0, gp0)
    MKTASK(t + 256, la1, tk1, gp1)
#undef MKTASK
  }

  // ---- P2 constants (t<192): task = (ext row r2, group qq) ----
  // reads 12 consecutive x,y floats; emits 5 channels x 4 outputs (b128 each)
  const int r2 = t >> 3;            // 0..23
  const int qq = t & 7;             // group-1: outputs tile w = 4qq..4qq+3
  const int rdx = r2 * XSTR + 4 * qq;   // x at [rdx..rdx+11]; y at +APL
  const int wwr = r2 * WRS + 4 * qq;    // + c*WCSTR

  // ---- P3 constants (t<80): task = (channel c3, w-group wq, h-half) ----
  const int c3 = t >> 4;            // 0..4
  const int wq3 = (t & 15) >> 1;    // 0..7
  const int hf3 = t & 1;            // 0..1
  const int rb3 = c3 * WCSTR + (hf3 * 8) * WRS + 4 * wq3;  // + i*WRS, i=0..15
  const int wb3 = c3 * HCSTR + (hf3 * 8) * HRS + 4 * wq3;  // + hh*HRS

  // ---- P4 constants: thread owns w-pair (2p4, 2p4+1) at row h4 ----
  const int h4 = t >> 4, p4 = t & 15;
  const int hrOff = h4 * HRS + 2 * p4;   // + c*HCSTR (float2)

  // ---- D-window ring: 9 deep x 5 ch x 2 outputs (static idx -> VGPRs) ----
  float2 rg[9][5];
#pragma unroll
  for (int i = 0; i < 9; ++i)
#pragma unroll
    for (int c = 0; c < 5; ++c) { rg[i][c].x = 0.f; rg[i][c].y = 0.f; }
  float2 rn0 = {0, 0}, rn1 = {0, 0}, rn2 = {0, 0}, rn3 = {0, 0}, rn4 = {0, 0};
  float acc = 0.f;

  __syncthreads();   // zero-init visible

  // ---- prologue: prefetch slice k=0 ----
  float4 st0 = make_float4(0, 0, 0, 0), st1 = st0;
  bool ps0 = false, ps1 = false;
  if (g0 >= 0) {
    const long so = (long)g0 * HW;
    ps0 = tk0; if (ps0) st0 = *(const float4*)(gp0 + so);
    ps1 = tk1; if (ps1) st1 = *(const float4*)(gp1 + so);
  }

  for (int ko = 0; ko < 3; ++ko) {
#pragma unroll
    for (int jj = 0; jj < 9; ++jj) {
      const int k = ko * 9 + jj;
      const int g = g0 + k;
      const bool gv = ((unsigned)g < (unsigned)DD);   // block-uniform

      // ---- store staged regs (slice k) -> planes ----
      if (gv) {
        if (ps0) *(float4*)&sb[la0] = st0;
        if (ps1) *(float4*)&sb[la1] = st1;
      }
      // ---- prefetch slice k+1 (in flight across all barriers) ----
      {
        const int gn = g + 1;
        const bool nv = (k + 1 < NITER) && ((unsigned)gn < (unsigned)DD);
        const long so = (long)gn * HW;
        ps0 = tk0 && nv; if (ps0) st0 = *(const float4*)(gp0 + so);
        ps1 = tk1 && nv; if (ps1) st1 = *(const float4*)(gp1 + so);
      }

      float2 hv0 = {0, 0}, hv1 = {0, 0}, hv2 = {0, 0}, hv3 = {0, 0}, hv4 = {0, 0};
      if (gv) {
        bar_lgkm();  // A: planes visible
        // ---- P2: W-filter; 192 tasks; contiguous b128 reads, b128 writes ----
        if (t < 192) {
          float xa[12], ya[12];
          {
            float4 X0 = *(const float4*)&sb[rdx];
            float4 X1 = *(const float4*)&sb[rdx + 4];
            float4 X2 = *(const float4*)&sb[rdx + 8];
            xa[0]=X0.x; xa[1]=X0.y; xa[2]=X0.z; xa[3]=X0.w;
            xa[4]=X1.x; xa[5]=X1.y; xa[6]=X1.z; xa[7]=X1.w;
            xa[8]=X2.x; xa[9]=X2.y; xa[10]=X2.z; xa[11]=X2.w;
            float4 Y0 = *(const float4*)&sb[APL + rdx];
            float4 Y1 = *(const float4*)&sb[APL + rdx + 4];
            float4 Y2 = *(const float4*)&sb[APL + rdx + 8];
            ya[0]=Y0.x; ya[1]=Y0.y; ya[2]=Y0.z; ya[3]=Y0.w;
            ya[4]=Y1.x; ya[5]=Y1.y; ya[6]=Y1.z; ya[7]=Y1.w;
            ya[8]=Y2.x; ya[9]=Y2.y; ya[10]=Y2.z; ya[11]=Y2.w;
          }
#define EMITCH(CIDX, EXPR)                                                 \
          {                                                                \
            float qv[12];                                                  \
            _Pragma("unroll")                                              \
            for (int i = 0; i < 12; ++i) qv[i] = (EXPR);                   \
            float o0 = ((qv[0]+qv[1])+(qv[2]+qv[3]))+                      \
                       ((qv[4]+qv[5])+(qv[6]+qv[7]))+qv[8];                \
            float o1 = o0 + qv[9]  - qv[0];                                \
            float o2 = o1 + qv[10] - qv[1];                                \
            float o3 = o2 + qv[11] - qv[2];                                \
            *(float4*)&ws[(CIDX) * WCSTR + wwr] = make_float4(o0,o1,o2,o3);\
          }
          EMITCH(0, xa[i])
          EMITCH(1, ya[i])
          EMITCH(2, xa[i] * xa[i])
          EMITCH(3, ya[i] * ya[i])
          EMITCH(4, xa[i] * ya[i])
#undef EMITCH
        }
        bar_lgkm();  // B
        // ---- P3: H-filter; 80 tasks; 4-wide sliding column sums ----
        if (t < 80) {
          float4 v[16];
#pragma unroll
          for (int i = 0; i < 9; ++i) v[i] = *(const float4*)&ws[rb3 + i * WRS];
          float4 s = f4add(f4add(f4add(f4add(v[0], v[1]), f4add(v[2], v[3])),
                                 f4add(f4add(v[4], v[5]), f4add(v[6], v[7]))),
                           v[8]);
          *(float4*)&hs[wb3] = s;
#pragma unroll
          for (int hh = 1; hh < 8; ++hh) {
            v[hh + 8] = *(const float4*)&ws[rb3 + (hh + 8) * WRS];
            s = f4pm(s, v[hh + 8], v[hh - 1]);
            *(float4*)&hs[wb3 + hh * HRS] = s;
          }
        }
        bar_lgkm();  // C
        hv0 = *(const float2*)&hs[hrOff];
        hv1 = *(const float2*)&hs[HCSTR + hrOff];
        hv2 = *(const float2*)&hs[2 * HCSTR + hrOff];
        hv3 = *(const float2*)&hs[3 * HCSTR + hrOff];
        hv4 = *(const float2*)&hs[4 * HCSTR + hrOff];
      }

      // ---- D running sums; ring[jj] static -> no register shifting ----
      rn0.x += hv0.x - rg[jj][0].x; rg[jj][0].x = hv0.x;
      rn0.y += hv0.y - rg[jj][0].y; rg[jj][0].y = hv0.y;
      rn1.x += hv1.x - rg[jj][1].x; rg[jj][1].x = hv1.x;
      rn1.y += hv1.y - rg[jj][1].y; rg[jj][1].y = hv1.y;
      rn2.x += hv2.x - rg[jj][2].x; rg[jj][2].x = hv2.x;
      rn2.y += hv2.y - rg[jj][2].y; rg[jj][2].y = hv2.y;
      rn3.x += hv3.x - rg[jj][3].x; rg[jj][3].x = hv3.x;
      rn3.y += hv3.y - rg[jj][3].y; rg[jj][3].y = hv3.y;
      rn4.x += hv4.x - rg[jj][4].x; rg[jj][4].x = hv4.x;
      rn4.y += hv4.y - rg[jj][4].y; rg[jj][4].y = hv4.y;

      if (k >= 8) {
        const int d = dc0 + (k - 8);
        if (d < DD) {                 // block-uniform tail guard
          {
            float cross = fmaf(-rn0.x * INV_WS, rn1.x, rn4.x);
            float xv = fmaxf(fmaf(-rn0.x * INV_WS, rn0.x, rn2.x), EPS);
            float yv = fmaxf(fmaf(-rn1.x * INV_WS, rn1.x, rn3.x), EPS);
            acc += (cross * cross) * __builtin_amdgcn_rcpf(xv * yv);
          }
          {
            float cross = fmaf(-rn0.y * INV_WS, rn1.y, rn4.y);
            float xv = fmaxf(fmaf(-rn0.y * INV_WS, rn0.y, rn2.y), EPS);
            float yv = fmaxf(fmaf(-rn1.y * INV_WS, rn1.y, rn3.y), EPS);
            acc += (cross * cross) * __builtin_amdgcn_rcpf(xv * yv);
          }
        }
      }
    }
  }

  // ---- block reduction ----
#pragma unroll
  for (int o = 32; o > 0; o >>= 1) acc += __shfl_down(acc, o);
  if ((t & 63) == 0) red[t >> 6] = acc;
  __syncthreads();
  if (t == 0) {
    int bid = (bz * HT + blockIdx.y) * WT + blockIdx.x;
    partials[bid] = (red[0] + red[1]) + (red[2] + red[3]);
  }
}

__global__ void __launch_bounds__(256) k_finalize(
    const float* __restrict__ partials, float* __restrict__ out)
{
  __shared__ double red[256];
  double s = 0.0;
  for (int i = threadIdx.x; i < NBLK; i += 256) s += (double)partials[i];
  red[threadIdx.x] = s;
  __syncthreads();
  for (int o = 128; o > 0; o >>= 1) {
    if (threadIdx.x < o) red[threadIdx.x] += red[threadIdx.x + o];
    __syncthreads();
  }
  if (threadIdx.x == 0) {
    const double Nvox = (double)BB * DD * HH * WW;
    out[0] = (float)(-red[0] / Nvox);
  }
}

extern "C" void kernel_launch(void* const* d_in, const int* in_sizes, int n_in,
                              void* d_out, int out_size, void* d_ws, size_t ws_size,
                              hipStream_t stream) {
  (void)in_sizes; (void)n_in; (void)out_size; (void)ws_size;
  const float* x = (const float*)d_in[0];
  const float* y = (const float*)d_in[1];
  float* out = (float*)d_out;
  float* partials = (float*)d_ws;

  dim3 grid(WT, HT, BB * NCH);
  k_lncc<<<grid, 256, 0, stream>>>(x, y, partials);
  k_finalize<<<1, 256, 0, stream>>>(partials, out);
}